// Round 7
// baseline (3559.336 us; speedup 1.0000x reference)
//
#include <hip/hip_runtime.h>
#include <math.h>

typedef _Float16 f16;
typedef _Float16 f16x8 __attribute__((ext_vector_type(8)));
typedef float f32x4 __attribute__((ext_vector_type(4)));

#define MFMA16(A_, B_, C_) __builtin_amdgcn_mfma_f32_16x16x32_f16((A_), (B_), (C_), 0, 0, 0)
#define SWZ(m) ((((m) & 7) ^ (((m) & 8) >> 2)) << 4)

__device__ __forceinline__ float rcpf_(float x) { return __builtin_amdgcn_rcpf(x); }
__device__ __forceinline__ float rsqf_(float x) { return __builtin_amdgcn_rsqf(x); }
__device__ __forceinline__ float sigf(float x) { return rcpf_(1.0f + __expf(-x)); }
__device__ __forceinline__ float tanhf_(float x) { return 1.0f - 2.0f * rcpf_(__expf(2.0f * x) + 1.0f); }

// ---------------- workspace layout (bytes) ----------------
static const size_t OFF_ENCIN = 0;                         // f16 [1024][256][32]
static const size_t OFF_DECIN = 16777216;                  // f16 [48][256][32]
static const size_t OFF_WENC  = OFF_DECIN + 786432;        // f16 [9][48][64][8]
static const size_t OFF_WDEC  = OFF_WENC + 442368;         // f16 [9][48][64][8]
static const size_t OFF_W32   = OFF_WDEC + 442368;         // float[768]
static const size_t OFF_BE    = OFF_W32 + 3072;            // float[1024]
static const size_t OFF_BD    = OFF_BE + 4096;             // float[1024]
static const size_t OFF_HENC  = OFF_BD + 4096;             // f16 [256][256]
static const size_t OFF_EOUT  = OFF_HENC + 131072;         // float[256]
static const size_t OFF_XST   = OFF_EOUT + 1024;           // float[48][32][2]
static const size_t OFF_OST   = OFF_XST + 12288;           // float[128]
static const size_t OFF_CNT   = OFF_OST + 512;             // int[64]

struct P {
  const float *Xe, *Xd, *Xge, *Xgd, *Wge, *bge, *Wgd, *bgd;
  const float *eWih, *eWhh, *ebih, *ebhh, *eWo, *ebo;
  const float *dWih, *dWhh, *dbih, *dbhh, *dWo, *dbo;
  const float *bn1g, *bn1b, *bnTg, *bnTb;
  f16 *encin, *decin, *wencf, *wdecf;
  float *w32, *bE, *bD;
  f16 *henc;
  float *eout, *xst, *ost;
  int *cnt;
  float *out;
};

// ---------------- prep kernels ----------------
__global__ void prep1(P p) {
  const int blk = blockIdx.x, tid = threadIdx.x;
  __shared__ float swg[512];
  __shared__ float sbg[16];
  if (blk < 1024) {                       // enc_in: i = b*1024 + t
    for (int i = tid; i < 512; i += 256) swg[i] = p.Wge[i];
    if (tid < 16) sbg[tid] = p.bge[tid];
    __syncthreads();
    const int i = blk * 256 + tid;
    const int b = i >> 10, t = i & 1023;
    const float* xg = p.Xge + (size_t)(b * 1024 + t) * 32;
    const float* xe = p.Xe + (size_t)(b * 1024 + t) * 16;
    f16* o = p.encin + (size_t)(t * 256 + b) * 32;
    float xgv[32];
#pragma unroll
    for (int k = 0; k < 32; ++k) xgv[k] = xg[k];
#pragma unroll
    for (int c = 0; c < 16; ++c) o[c] = (f16)xe[c];
#pragma unroll 4
    for (int r = 0; r < 16; ++r) {
      float acc = sbg[r];
#pragma unroll
      for (int k = 0; k < 32; ++k) acc += swg[r * 32 + k] * xgv[k];
      o[16 + r] = (f16)acc;
    }
  } else if (blk < 1072) {                // dec_in: i = b*48 + t
    for (int i = tid; i < 512; i += 256) swg[i] = p.Wgd[i];
    if (tid < 16) sbg[tid] = p.bgd[tid];
    __syncthreads();
    const int i = (blk - 1024) * 256 + tid;
    const int b = i / 48, t = i - b * 48;
    const float* xg = p.Xgd + (size_t)(b * 48 + t) * 32;
    const float* xd = p.Xd + (size_t)(b * 48 + t) * 16;
    f16* o = p.decin + (size_t)(t * 256 + b) * 32;
    float xgv[32];
#pragma unroll
    for (int k = 0; k < 32; ++k) xgv[k] = xg[k];
#pragma unroll
    for (int c = 0; c < 16; ++c) o[c] = (f16)xd[c];
#pragma unroll 4
    for (int r = 0; r < 16; ++r) {
      float acc = sbg[r];
#pragma unroll
      for (int k = 0; k < 32; ++k) acc += swg[r * 32 + k] * xgv[k];
      o[16 + r] = (f16)acc;
    }
  } else if (blk < 1180) {                // encoder weight fragments
    const int i = (blk - 1072) * 256 + tid;     // [0, 27648)
    const int kt = i / 3072, r2 = i - kt * 3072;
    const int nt = r2 >> 6, l = r2 & 63;
    const int n = nt * 16 + (l & 15), g = l >> 4;
    f16* o = p.wencf + (size_t)i * 8;
#pragma unroll
    for (int j = 0; j < 8; ++j) {
      const int k = g * 8 + j;
      o[j] = (f16)((kt == 0) ? p.eWih[n * 32 + k] : p.eWhh[n * 256 + (kt - 1) * 32 + k]);
    }
  } else if (blk < 1288) {                // decoder weight fragments
    const int i = (blk - 1180) * 256 + tid;
    const int kt = i / 3072, r2 = i - kt * 3072;
    const int nt = r2 >> 6, l = r2 & 63;
    const int n = nt * 16 + (l & 15), g = l >> 4;
    f16* o = p.wdecf + (size_t)i * 8;
#pragma unroll
    for (int j = 0; j < 8; ++j) {
      const int k = g * 8 + j;
      o[j] = (f16)((kt == 0) ? p.dWih[n * 33 + k] : p.dWhh[n * 256 + (kt - 1) * 32 + k]);
    }
  } else if (blk == 1288) {               // w32 column + zero stats/counters
    for (int i = tid; i < 768; i += 256) p.w32[i] = p.dWih[i * 33 + 32];
    for (int i = tid; i < 128; i += 256) p.ost[i] = 0.f;
    if (tid < 64) p.cnt[tid] = 0;
  } else if (blk == 1289) {               // encoder combined biases
    for (int i = tid; i < 1024; i += 256) {
      float v;
      if (i < 512) v = p.ebih[i] + p.ebhh[i];
      else if (i < 768) v = p.ebih[i];
      else v = p.ebhh[i - 256];
      p.bE[i] = v;
    }
  } else {                                // decoder combined biases
    for (int i = tid; i < 1024; i += 256) {
      float v;
      if (i < 512) v = p.dbih[i] + p.dbhh[i];
      else if (i < 768) v = p.dbih[i];
      else v = p.dbhh[i - 256];
      p.bD[i] = v;
    }
  }
}

__global__ void prep2(P p) {              // decoder x-channel BN stats per step
  const int i = blockIdx.x * 256 + threadIdx.x;
  if (i >= 48 * 32) return;
  const int s = i >> 5, c = i & 31;
  float s1 = 0.f, s2 = 0.f;
  for (int b = 0; b < 256; ++b) {
    const float v = (float)p.decin[(size_t)(s * 256 + b) * 32 + c];
    s1 += v; s2 += v * v;
  }
  const float mu = s1 * (1.0f / 256.0f);
  p.xst[i * 2] = mu;
  p.xst[i * 2 + 1] = s2 * (1.0f / 256.0f) - mu * mu;
}

// ---------------- encoder: 16 WGs x 1024 thr (16 waves), 1024 steps ----------------
// wave w owns unit-tile w (units 16w..16w+15): chains R (nt=w), Z (nt=16+w), N (nt=32+w)
__global__ __launch_bounds__(1024, 4) void enc_kernel(P p) {
  __shared__ f16 sWL[49152];     // W k-tiles 7,8 all 48 nt (98304 B)
  __shared__ f16 sH[8192];       // h double buffer, swizzled (16384 B)
  __shared__ float sRed[512];
  const int tid = threadIdx.x;
  const int l = tid & 63, w = tid >> 6;        // w 0..15
  const int g = l >> 4, m16 = l & 15;
  const int swzA = SWZ(m16);
  const int bg = blockIdx.x * 16;

  { // stage LDS W (kts 7,8): 6144 int4
    const int4* src = (const int4*)(p.wencf + 172032);
    int4* dst = (int4*)sWL;
#pragma unroll
    for (int i = 0; i < 6; ++i) dst[tid + i * 1024] = src[tid + i * 1024];
  }
  { // zero h buffers: 4096 ints
    int* hz = (int*)sH;
#pragma unroll
    for (int i = 0; i < 4; ++i) hz[tid + i * 1024] = 0;
  }
  // W kt0..6 in registers: 21 frags = 84 VGPR
  f16x8 Wr[7][3];
#pragma unroll
  for (int kt = 0; kt < 7; ++kt) {
    Wr[kt][0] = *(const f16x8*)(p.wencf + ((size_t)(kt * 48 + w) * 64 + l) * 8);
    Wr[kt][1] = *(const f16x8*)(p.wencf + ((size_t)(kt * 48 + 16 + w) * 64 + l) * 8);
    Wr[kt][2] = *(const f16x8*)(p.wencf + ((size_t)(kt * 48 + 32 + w) * 64 + l) * 8);
  }
  const int u = 16 * w + m16;                  // this lane's unit
  const float br = p.bE[u], bz = p.bE[256 + u], bi = p.bE[512 + u], bh = p.bE[768 + u];
  float hp[4] = {0.f, 0.f, 0.f, 0.f};
  __syncthreads();

  int ph = 0;
#pragma unroll 1
  for (int t = 0; t < 1024; ++t) {
    const f16x8 xf = *(const f16x8*)(p.encin + ((size_t)t * 256 + bg + m16) * 32 + 8 * g);
    f32x4 aR = {br, br, br, br}, aZ = {bz, bz, bz, bz}, aNh = {bh, bh, bh, bh};
#pragma unroll
    for (int kk = 1; kk <= 6; ++kk) {
      const f16x8 a = *(const f16x8*)((const char*)sH + ph * 8192 + m16 * 512 +
                                      ((64 * (kk - 1) + 16 * g) ^ swzA));
      aR = MFMA16(a, Wr[kk][0], aR);
      aZ = MFMA16(a, Wr[kk][1], aZ);
      aNh = MFMA16(a, Wr[kk][2], aNh);
    }
#pragma unroll
    for (int kk = 7; kk <= 8; ++kk) {
      const f16x8 a = *(const f16x8*)((const char*)sH + ph * 8192 + m16 * 512 +
                                      ((64 * (kk - 1) + 16 * g) ^ swzA));
      const char* wb = (const char*)sWL + (kk - 7) * 49152;
      const f16x8 q0 = *(const f16x8*)(wb + ((0 + w) * 64 + l) * 16);
      const f16x8 q1 = *(const f16x8*)(wb + ((16 + w) * 64 + l) * 16);
      const f16x8 q2 = *(const f16x8*)(wb + ((32 + w) * 64 + l) * 16);
      aR = MFMA16(a, q0, aR);
      aZ = MFMA16(a, q1, aZ);
      aNh = MFMA16(a, q2, aNh);
    }
    f32x4 aNi = {bi, bi, bi, bi};
    aR = MFMA16(xf, Wr[0][0], aR);
    aZ = MFMA16(xf, Wr[0][1], aZ);
    aNi = MFMA16(xf, Wr[0][2], aNi);
    // epilogue: 4 gate-sets per lane (unit u, batch rows 4g+q)
    {
      char* hw = (char*)sH + (ph ^ 1) * 8192;
#pragma unroll
      for (int q = 0; q < 4; ++q) {
        const int m = 4 * g + q;
        const float r = sigf(aR[q]);
        const float z = sigf(aZ[q]);
        const float n = tanhf_(aNi[q] + r * aNh[q]);
        const f16 h = (f16)(n + z * (hp[q] - n));
        hp[q] = (float)h;
        *(f16*)(hw + m * 512 + ((2 * u) ^ SWZ(m))) = h;
      }
    }
    __syncthreads();
    ph ^= 1;
  }
  // finalize: store h, compute enc_out
  {
    const char* hb = (const char*)sH + ph * 8192;
    if (tid < 512) {
      const int m = tid & 15, grp = tid >> 4;
      const f16x8 hv = *(const f16x8*)(hb + m * 512 + ((16 * grp) ^ SWZ(m)));
      *(f16x8*)(p.henc + (size_t)(bg + m) * 256 + 8 * grp) = hv;
      float part = 0.f;
#pragma unroll
      for (int jj = 0; jj < 8; ++jj) part += (float)hv[jj] * p.eWo[8 * grp + jj];
      sRed[m * 32 + grp] = part;
    }
    __syncthreads();
    if (tid < 16) {
      float o = p.ebo[0];
#pragma unroll 8
      for (int k = 0; k < 32; ++k) o += sRed[tid * 32 + k];
      p.eout[bg + tid] = o;
    }
  }
}

// ---------------- decoder: 16 WGs x 1024 thr, 48 steps + per-step counter sync ----------------
__global__ __launch_bounds__(1024, 4) void dec_kernel(P p) {
  __shared__ f16 sWL[49152];
  __shared__ f16 sH[8192];
  __shared__ f16 sDin[1024];     // [16][64] f16, swizzled by (m&7)<<4
  __shared__ float sRed[512];
  __shared__ float sOutv[16];
  __shared__ float sO32[16];
  const int tid = threadIdx.x;
  const int l = tid & 63, w = tid >> 6;
  const int g = l >> 4, m16 = l & 15;
  const int sw16 = (m16 & 7) << 4;
  const int swzA = SWZ(m16);
  const int bg = blockIdx.x * 16;

  { // stage LDS W (kts 7,8)
    const int4* src = (const int4*)(p.wdecf + 172032);
    int4* dst = (int4*)sWL;
#pragma unroll
    for (int i = 0; i < 6; ++i) dst[tid + i * 1024] = src[tid + i * 1024];
  }
  if (tid < 512) { // h <- h_enc (swizzled), buffer 0
    const int m = tid & 15, grp = tid >> 4;
    const f16x8 hv = *(const f16x8*)(p.henc + (size_t)(bg + m) * 256 + 8 * grp);
    *(f16x8*)((char*)sH + m * 512 + ((16 * grp) ^ SWZ(m))) = hv;
  }
  if (tid < 128) ((int4*)sDin)[tid] = int4{0, 0, 0, 0};
  f16x8 Wr[7][3];
#pragma unroll
  for (int kt = 0; kt < 7; ++kt) {
    Wr[kt][0] = *(const f16x8*)(p.wdecf + ((size_t)(kt * 48 + w) * 64 + l) * 8);
    Wr[kt][1] = *(const f16x8*)(p.wdecf + ((size_t)(kt * 48 + 16 + w) * 64 + l) * 8);
    Wr[kt][2] = *(const f16x8*)(p.wdecf + ((size_t)(kt * 48 + 32 + w) * 64 + l) * 8);
  }
  const int u = 16 * w + m16;
  const float br = p.bD[u], bz = p.bD[256 + u], bi = p.bD[512 + u], bh = p.bD[768 + u];
  const float w32r = p.w32[u], w32z = p.w32[256 + u], w32n = p.w32[512 + u];
  float hp[4];
#pragma unroll
  for (int q = 0; q < 4; ++q)
    hp[q] = (float)p.henc[(size_t)(bg + 4 * g + q) * 256 + u];
  // eout -> sOutv, push stats for step 0
  if (tid < 16) sOutv[tid] = p.eout[bg + tid];
  __syncthreads();
  if (tid == 0) {
    float s1 = 0.f, s2 = 0.f;
#pragma unroll
    for (int k = 0; k < 16; ++k) { const float v = sOutv[k]; s1 += v; s2 += v * v; }
    atomicAdd(&p.ost[0], s1);
    atomicAdd(&p.ost[1], s2);
    __hip_atomic_fetch_add(&p.cnt[0], 1, __ATOMIC_RELEASE, __HIP_MEMORY_SCOPE_AGENT);
  }

  int ph = 0;
#pragma unroll 1
  for (int t = 0; t < 48; ++t) {
    // prefetch BN inputs for this step (no dependence on the counter)
    const int mp = tid & 15, cp = (tid >> 4) & 31;
    float xq = 0.f, mx = 0.f, vx = 1.f, gc = 0.f, bc = 0.f;
    if (tid < 512) {
      xq = (float)p.decin[((size_t)t * 256 + bg + mp) * 32 + cp];
      mx = p.xst[(t * 32 + cp) * 2];
      vx = p.xst[(t * 32 + cp) * 2 + 1];
      gc = (t == 0) ? p.bn1g[cp] : p.bnTg[(t - 1) * 33 + cp];
      bc = (t == 0) ? p.bn1b[cp] : p.bnTb[(t - 1) * 33 + cp];
    }
    float gK = 0.f, bK = 0.f;
    if (tid < 16) {
      gK = (t == 0) ? p.bn1g[32] : p.bnTg[(t - 1) * 33 + 32];
      bK = (t == 0) ? p.bn1b[32] : p.bnTb[(t - 1) * 33 + 32];
    }
    // (a) h-part MFMAs first (no dinp dependency)
    f32x4 aR = {br, br, br, br}, aZ = {bz, bz, bz, bz}, aNh = {bh, bh, bh, bh};
#pragma unroll
    for (int kk = 1; kk <= 6; ++kk) {
      const f16x8 a = *(const f16x8*)((const char*)sH + ph * 8192 + m16 * 512 +
                                      ((64 * (kk - 1) + 16 * g) ^ swzA));
      aR = MFMA16(a, Wr[kk][0], aR);
      aZ = MFMA16(a, Wr[kk][1], aZ);
      aNh = MFMA16(a, Wr[kk][2], aNh);
    }
#pragma unroll
    for (int kk = 7; kk <= 8; ++kk) {
      const f16x8 a = *(const f16x8*)((const char*)sH + ph * 8192 + m16 * 512 +
                                      ((64 * (kk - 1) + 16 * g) ^ swzA));
      const char* wb = (const char*)sWL + (kk - 7) * 49152;
      const f16x8 q0 = *(const f16x8*)(wb + ((0 + w) * 64 + l) * 16);
      const f16x8 q1 = *(const f16x8*)(wb + ((16 + w) * 64 + l) * 16);
      const f16x8 q2 = *(const f16x8*)(wb + ((32 + w) * 64 + l) * 16);
      aR = MFMA16(a, q0, aR);
      aZ = MFMA16(a, q1, aZ);
      aNh = MFMA16(a, q2, aNh);
    }
    // (b) wait for batch stats of this step, then build sO32 + sDin
    if (tid == 0) {
      while (__hip_atomic_load(&p.cnt[t], __ATOMIC_ACQUIRE, __HIP_MEMORY_SCOPE_AGENT) < 16)
        __builtin_amdgcn_s_sleep(1);
    }
    __syncthreads();
    if (tid < 16) {
      const float S1 = __hip_atomic_load(&p.ost[2 * t], __ATOMIC_RELAXED, __HIP_MEMORY_SCOPE_AGENT);
      const float S2 = __hip_atomic_load(&p.ost[2 * t + 1], __ATOMIC_RELAXED, __HIP_MEMORY_SCOPE_AGENT);
      const float mu = S1 * (1.0f / 256.0f);
      const float var = S2 * (1.0f / 256.0f) - mu * mu;
      sO32[tid] = gK * (sOutv[tid] - mu) * rsqf_(var + 1e-5f) + bK;
    }
    if (tid < 512)
      *(f16*)((char*)sDin + mp * 128 + ((2 * cp) ^ ((mp & 7) << 4))) =
          (f16)(gc * (xq - mx) * rsqf_(vx + 1e-5f) + bc);
    __syncthreads();
    // (c) kt0 on dinp, then epilogue with rank-1 out-channel term
    f32x4 aNi = {bi, bi, bi, bi};
    {
      const f16x8 a = *(const f16x8*)((const char*)sDin + m16 * 128 + ((16 * g) ^ sw16));
      aR = MFMA16(a, Wr[0][0], aR);
      aZ = MFMA16(a, Wr[0][1], aZ);
      aNi = MFMA16(a, Wr[0][2], aNi);
    }
    {
      char* hw = (char*)sH + (ph ^ 1) * 8192;
#pragma unroll
      for (int q = 0; q < 4; ++q) {
        const int m = 4 * g + q;
        const float o32m = sO32[m];
        const float r = sigf(aR[q] + o32m * w32r);
        const float z = sigf(aZ[q] + o32m * w32z);
        const float n = tanhf_(aNi[q] + o32m * w32n + r * aNh[q]);
        const f16 h = (f16)(n + z * (hp[q] - n));
        hp[q] = (float)h;
        *(f16*)(hw + m * 512 + ((2 * u) ^ SWZ(m))) = h;
      }
    }
    __syncthreads();   // h_new complete
    // (d) out = h_new @ Wo + bo; push stats for t+1
    if (tid < 512) {
      const int m = tid & 15, grp = tid >> 4;
      const char* hb = (const char*)sH + (ph ^ 1) * 8192;
      const f16x8 hv = *(const f16x8*)(hb + m * 512 + ((16 * grp) ^ SWZ(m)));
      float part = 0.f;
#pragma unroll
      for (int jj = 0; jj < 8; ++jj) part += (float)hv[jj] * p.dWo[8 * grp + jj];
      sRed[m * 32 + grp] = part;
    }
    __syncthreads();
    if (tid < 16) {
      float o = p.dbo[0];
#pragma unroll 8
      for (int k = 0; k < 32; ++k) o += sRed[tid * 32 + k];
      p.out[(size_t)(bg + tid) * 48 + t] = o;
      sOutv[tid] = o;
    }
    __syncthreads();
    if (t < 47 && tid == 0) {
      float s1 = 0.f, s2 = 0.f;
#pragma unroll
      for (int k = 0; k < 16; ++k) { const float v = sOutv[k]; s1 += v; s2 += v * v; }
      atomicAdd(&p.ost[2 * (t + 1)], s1);
      atomicAdd(&p.ost[2 * (t + 1) + 1], s2);
      __hip_atomic_fetch_add(&p.cnt[t + 1], 1, __ATOMIC_RELEASE, __HIP_MEMORY_SCOPE_AGENT);
    }
    ph ^= 1;
  }
}

// ---------------- launcher ----------------
extern "C" void kernel_launch(void* const* d_in, const int* in_sizes, int n_in,
                              void* d_out, int out_size, void* d_ws, size_t ws_size,
                              hipStream_t stream) {
  char* ws = (char*)d_ws;
  P p;
  p.Xe   = (const float*)d_in[0];
  p.Xd   = (const float*)d_in[1];
  p.Xge  = (const float*)d_in[2];
  p.Xgd  = (const float*)d_in[3];
  p.Wge  = (const float*)d_in[4];
  p.bge  = (const float*)d_in[5];
  p.Wgd  = (const float*)d_in[6];
  p.bgd  = (const float*)d_in[7];
  p.eWih = (const float*)d_in[8];
  p.eWhh = (const float*)d_in[9];
  p.ebih = (const float*)d_in[10];
  p.ebhh = (const float*)d_in[11];
  p.eWo  = (const float*)d_in[12];
  p.ebo  = (const float*)d_in[13];
  p.dWih = (const float*)d_in[14];
  p.dWhh = (const float*)d_in[15];
  p.dbih = (const float*)d_in[16];
  p.dbhh = (const float*)d_in[17];
  p.dWo  = (const float*)d_in[18];
  p.dbo  = (const float*)d_in[19];
  p.bn1g = (const float*)d_in[20];
  p.bn1b = (const float*)d_in[21];
  p.bnTg = (const float*)d_in[22];
  p.bnTb = (const float*)d_in[23];
  p.encin = (f16*)(ws + OFF_ENCIN);
  p.decin = (f16*)(ws + OFF_DECIN);
  p.wencf = (f16*)(ws + OFF_WENC);
  p.wdecf = (f16*)(ws + OFF_WDEC);
  p.w32   = (float*)(ws + OFF_W32);
  p.bE    = (float*)(ws + OFF_BE);
  p.bD    = (float*)(ws + OFF_BD);
  p.henc  = (f16*)(ws + OFF_HENC);
  p.eout  = (float*)(ws + OFF_EOUT);
  p.xst   = (float*)(ws + OFF_XST);
  p.ost   = (float*)(ws + OFF_OST);
  p.cnt   = (int*)(ws + OFF_CNT);
  p.out   = (float*)d_out;

  prep1<<<dim3(1291), dim3(256), 0, stream>>>(p);
  prep2<<<dim3(6), dim3(256), 0, stream>>>(p);
  enc_kernel<<<dim3(16), dim3(1024), 0, stream>>>(p);
  dec_kernel<<<dim3(16), dim3(1024), 0, stream>>>(p);
}

// Round 10
// 3367.097 us; speedup vs baseline: 1.0571x; 1.0571x over previous
//
#include <hip/hip_runtime.h>
#include <math.h>

typedef _Float16 f16;
typedef _Float16 f16x8 __attribute__((ext_vector_type(8)));
typedef float f32x4 __attribute__((ext_vector_type(4)));

#define MFMA16(A_, B_, C_) __builtin_amdgcn_mfma_f32_16x16x32_f16((A_), (B_), (C_), 0, 0, 0)
#define SWZ(m) ((((m) & 7) ^ (((m) & 8) >> 2)) << 4)

__device__ __forceinline__ float rcpf_(float x) { return __builtin_amdgcn_rcpf(x); }
__device__ __forceinline__ float rsqf_(float x) { return __builtin_amdgcn_rsqf(x); }
__device__ __forceinline__ float sigf(float x) { return rcpf_(1.0f + __expf(-x)); }
__device__ __forceinline__ float tanhf_(float x) { return 1.0f - 2.0f * rcpf_(__expf(2.0f * x) + 1.0f); }

// ---------------- workspace layout (bytes) ----------------
static const size_t OFF_ENCIN = 0;                         // f16 [1024][256][32]
static const size_t OFF_DECIN = 16777216;                  // f16 [48][256][32]
static const size_t OFF_WENC  = OFF_DECIN + 786432;        // f16 [9][48][64][8]
static const size_t OFF_WDEC  = OFF_WENC + 442368;         // f16 [9][48][64][8]
static const size_t OFF_W32   = OFF_WDEC + 442368;         // float[768]
static const size_t OFF_BE    = OFF_W32 + 3072;            // float[1024]
static const size_t OFF_BD    = OFF_BE + 4096;             // float[1024]
static const size_t OFF_HENC  = OFF_BD + 4096;             // f16 [256][256]
static const size_t OFF_EOUT  = OFF_HENC + 131072;         // float[256]
static const size_t OFF_XST   = OFF_EOUT + 1024;           // float[48][32][2]
static const size_t OFF_OST   = OFF_XST + 12288;           // float[128]
static const size_t OFF_CNT   = OFF_OST + 512;             // int[64]

struct P {
  const float *Xe, *Xd, *Xge, *Xgd, *Wge, *bge, *Wgd, *bgd;
  const float *eWih, *eWhh, *ebih, *ebhh, *eWo, *ebo;
  const float *dWih, *dWhh, *dbih, *dbhh, *dWo, *dbo;
  const float *bn1g, *bn1b, *bnTg, *bnTb;
  f16 *encin, *decin, *wencf, *wdecf;
  float *w32, *bE, *bD;
  f16 *henc;
  float *eout, *xst, *ost;
  int *cnt;
  float *out;
};

// ---------------- prep kernels ----------------
__global__ void prep1(P p) {
  const int blk = blockIdx.x, tid = threadIdx.x;
  __shared__ float swg[512];
  __shared__ float sbg[16];
  if (blk < 1024) {                       // enc_in: i = b*1024 + t
    for (int i = tid; i < 512; i += 256) swg[i] = p.Wge[i];
    if (tid < 16) sbg[tid] = p.bge[tid];
    __syncthreads();
    const int i = blk * 256 + tid;
    const int b = i >> 10, t = i & 1023;
    const float* xg = p.Xge + (size_t)(b * 1024 + t) * 32;
    const float* xe = p.Xe + (size_t)(b * 1024 + t) * 16;
    f16* o = p.encin + (size_t)(t * 256 + b) * 32;
    float xgv[32];
#pragma unroll
    for (int k = 0; k < 32; ++k) xgv[k] = xg[k];
#pragma unroll
    for (int c = 0; c < 16; ++c) o[c] = (f16)xe[c];
#pragma unroll 4
    for (int r = 0; r < 16; ++r) {
      float acc = sbg[r];
#pragma unroll
      for (int k = 0; k < 32; ++k) acc += swg[r * 32 + k] * xgv[k];
      o[16 + r] = (f16)acc;
    }
  } else if (blk < 1072) {                // dec_in: i = b*48 + t
    for (int i = tid; i < 512; i += 256) swg[i] = p.Wgd[i];
    if (tid < 16) sbg[tid] = p.bgd[tid];
    __syncthreads();
    const int i = (blk - 1024) * 256 + tid;
    const int b = i / 48, t = i - b * 48;
    const float* xg = p.Xgd + (size_t)(b * 48 + t) * 32;
    const float* xd = p.Xd + (size_t)(b * 48 + t) * 16;
    f16* o = p.decin + (size_t)(t * 256 + b) * 32;
    float xgv[32];
#pragma unroll
    for (int k = 0; k < 32; ++k) xgv[k] = xg[k];
#pragma unroll
    for (int c = 0; c < 16; ++c) o[c] = (f16)xd[c];
#pragma unroll 4
    for (int r = 0; r < 16; ++r) {
      float acc = sbg[r];
#pragma unroll
      for (int k = 0; k < 32; ++k) acc += swg[r * 32 + k] * xgv[k];
      o[16 + r] = (f16)acc;
    }
  } else if (blk < 1180) {                // encoder weight fragments
    const int i = (blk - 1072) * 256 + tid;     // [0, 27648)
    const int kt = i / 3072, r2 = i - kt * 3072;
    const int nt = r2 >> 6, l = r2 & 63;
    const int n = nt * 16 + (l & 15), g = l >> 4;
    f16* o = p.wencf + (size_t)i * 8;
#pragma unroll
    for (int j = 0; j < 8; ++j) {
      const int k = g * 8 + j;
      o[j] = (f16)((kt == 0) ? p.eWih[n * 32 + k] : p.eWhh[n * 256 + (kt - 1) * 32 + k]);
    }
  } else if (blk < 1288) {                // decoder weight fragments
    const int i = (blk - 1180) * 256 + tid;
    const int kt = i / 3072, r2 = i - kt * 3072;
    const int nt = r2 >> 6, l = r2 & 63;
    const int n = nt * 16 + (l & 15), g = l >> 4;
    f16* o = p.wdecf + (size_t)i * 8;
#pragma unroll
    for (int j = 0; j < 8; ++j) {
      const int k = g * 8 + j;
      o[j] = (f16)((kt == 0) ? p.dWih[n * 33 + k] : p.dWhh[n * 256 + (kt - 1) * 32 + k]);
    }
  } else if (blk == 1288) {               // w32 column + zero stats/counters
    for (int i = tid; i < 768; i += 256) p.w32[i] = p.dWih[i * 33 + 32];
    for (int i = tid; i < 128; i += 256) p.ost[i] = 0.f;
    if (tid < 64) p.cnt[tid] = 0;
  } else if (blk == 1289) {               // encoder combined biases
    for (int i = tid; i < 1024; i += 256) {
      float v;
      if (i < 512) v = p.ebih[i] + p.ebhh[i];
      else if (i < 768) v = p.ebih[i];
      else v = p.ebhh[i - 256];
      p.bE[i] = v;
    }
  } else {                                // decoder combined biases
    for (int i = tid; i < 1024; i += 256) {
      float v;
      if (i < 512) v = p.dbih[i] + p.dbhh[i];
      else if (i < 768) v = p.dbih[i];
      else v = p.dbhh[i - 256];
      p.bD[i] = v;
    }
  }
}

__global__ void prep2(P p) {              // decoder x-channel BN stats per step
  const int i = blockIdx.x * 256 + threadIdx.x;
  if (i >= 48 * 32) return;
  const int s = i >> 5, c = i & 31;
  float s1 = 0.f, s2 = 0.f;
  for (int b = 0; b < 256; ++b) {
    const float v = (float)p.decin[(size_t)(s * 256 + b) * 32 + c];
    s1 += v; s2 += v * v;
  }
  const float mu = s1 * (1.0f / 256.0f);
  p.xst[i * 2] = mu;
  p.xst[i * 2 + 1] = s2 * (1.0f / 256.0f) - mu * mu;
}

// ---------------- encoder: 16 WGs x 512 thr (8 waves), 1024 steps ----------------
// wave w owns 6 chains: units {16w..16w+15, 128+16w..} x gates {R,Z,N}
// W kt1..8 (h-part) fully in registers (48 frags = 192 VGPR); kt0 (x-part) in LDS.
__global__ __attribute__((amdgpu_flat_work_group_size(512, 512), amdgpu_waves_per_eu(2)))
void enc_kernel(P p) {
  __shared__ f16 sW0[24576];     // kt0 W: 48 nt x 64 lanes x 8 f16 (49152 B)
  __shared__ f16 sH[8192];       // h double buffer, swizzled (16384 B)
  __shared__ float sRed[512];
  const int tid = threadIdx.x;
  const int l = tid & 63, w = tid >> 6;        // w 0..7
  const int g = l >> 4, m16 = l & 15;
  const int swzA = SWZ(m16);
  const int bg = blockIdx.x * 16;

  { // stage kt0 W into LDS: 3072 int4
    const int4* src = (const int4*)(p.wencf);
    int4* dst = (int4*)sW0;
#pragma unroll
    for (int i = 0; i < 6; ++i) dst[tid + i * 512] = src[tid + i * 512];
  }
  { // zero h buffers
    int* hz = (int*)sH;
#pragma unroll
    for (int i = 0; i < 8; ++i) hz[tid + i * 512] = 0;
  }
  const int nts[6] = {w, 8 + w, 16 + w, 24 + w, 32 + w, 40 + w};
  // W kt1..8 in registers: 48 frags = 192 VGPR
  f16x8 Wr[8][6];
#pragma unroll
  for (int kt = 1; kt <= 8; ++kt)
#pragma unroll
    for (int i = 0; i < 6; ++i)
      Wr[kt - 1][i] = *(const f16x8*)(p.wencf + ((size_t)(kt * 48 + nts[i]) * 64 + l) * 8);
  const int J1 = 16 * w + m16, J2 = 128 + J1;
  const float br1 = p.bE[J1], bz1 = p.bE[256 + J1], bi1 = p.bE[512 + J1], bh1 = p.bE[768 + J1];
  const float br2 = p.bE[J2], bz2 = p.bE[256 + J2], bi2 = p.bE[512 + J2], bh2 = p.bE[768 + J2];
  float hp1[4] = {0.f, 0.f, 0.f, 0.f}, hp2[4] = {0.f, 0.f, 0.f, 0.f};
  __syncthreads();

  int ph = 0;
#pragma unroll 1
  for (int t = 0; t < 1024; ++t) {
    const f16x8 xf = *(const f16x8*)(p.encin + ((size_t)t * 256 + bg + m16) * 32 + 8 * g);
    f32x4 aR0 = {0,0,0,0}, aR1 = {0,0,0,0}, aZ0 = {0,0,0,0}, aZ1 = {0,0,0,0};
    f32x4 aNh0 = {0,0,0,0}, aNh1 = {0,0,0,0};
    // kts 1..8: h part, W in registers
#pragma unroll
    for (int kk = 1; kk <= 8; ++kk) {
      const f16x8 a = *(const f16x8*)((const char*)sH + ph * 8192 + m16 * 512 +
                                      ((64 * (kk - 1) + 16 * g) ^ swzA));
      aR0 = MFMA16(a, Wr[kk - 1][0], aR0);
      aR1 = MFMA16(a, Wr[kk - 1][1], aR1);
      aZ0 = MFMA16(a, Wr[kk - 1][2], aZ0);
      aZ1 = MFMA16(a, Wr[kk - 1][3], aZ1);
      aNh0 = MFMA16(a, Wr[kk - 1][4], aNh0);
      aNh1 = MFMA16(a, Wr[kk - 1][5], aNh1);
    }
    // kt0: x part, W from LDS (read->MFMA interleaved to cap reg pressure)
    f32x4 aNi0 = {0,0,0,0}, aNi1 = {0,0,0,0};
    {
      const char* wb = (const char*)sW0;
      { const f16x8 q = *(const f16x8*)(wb + (nts[0] * 64 + l) * 16); aR0 = MFMA16(xf, q, aR0); }
      { const f16x8 q = *(const f16x8*)(wb + (nts[1] * 64 + l) * 16); aR1 = MFMA16(xf, q, aR1); }
      { const f16x8 q = *(const f16x8*)(wb + (nts[2] * 64 + l) * 16); aZ0 = MFMA16(xf, q, aZ0); }
      { const f16x8 q = *(const f16x8*)(wb + (nts[3] * 64 + l) * 16); aZ1 = MFMA16(xf, q, aZ1); }
      { const f16x8 q = *(const f16x8*)(wb + (nts[4] * 64 + l) * 16); aNi0 = MFMA16(xf, q, aNi0); }
      { const f16x8 q = *(const f16x8*)(wb + (nts[5] * 64 + l) * 16); aNi1 = MFMA16(xf, q, aNi1); }
    }
    // epilogue: gates -> new h (buffer ph^1); h_old lives in registers
    {
      char* hw = (char*)sH + (ph ^ 1) * 8192;
#pragma unroll
      for (int q = 0; q < 4; ++q) {
        const int m = 4 * g + q;
        const int sw = SWZ(m);
        const float r1 = sigf(aR0[q] + br1);
        const float z1 = sigf(aZ0[q] + bz1);
        const float n1 = tanhf_(aNi0[q] + bi1 + r1 * (aNh0[q] + bh1));
        const f16 h1 = (f16)(n1 + z1 * (hp1[q] - n1));
        hp1[q] = (float)h1;
        *(f16*)(hw + m * 512 + ((2 * J1) ^ sw)) = h1;
        const float r2 = sigf(aR1[q] + br2);
        const float z2 = sigf(aZ1[q] + bz2);
        const float n2 = tanhf_(aNi1[q] + bi2 + r2 * (aNh1[q] + bh2));
        const f16 h2 = (f16)(n2 + z2 * (hp2[q] - n2));
        hp2[q] = (float)h2;
        *(f16*)(hw + m * 512 + ((2 * J2) ^ sw)) = h2;
      }
    }
    __syncthreads();
    ph ^= 1;
  }
  // finalize: store h, compute enc_out
  {
    const char* hb = (const char*)sH + ph * 8192;
    const int m = tid & 15, grp = tid >> 4;
    const f16x8 hv = *(const f16x8*)(hb + m * 512 + ((16 * grp) ^ SWZ(m)));
    *(f16x8*)(p.henc + (size_t)(bg + m) * 256 + 8 * grp) = hv;
    float part = 0.f;
#pragma unroll
    for (int jj = 0; jj < 8; ++jj) part += (float)hv[jj] * p.eWo[8 * grp + jj];
    sRed[m * 32 + grp] = part;
    __syncthreads();
    if (tid < 16) {
      float o = p.ebo[0];
#pragma unroll 8
      for (int k = 0; k < 32; ++k) o += sRed[tid * 32 + k];
      p.eout[bg + tid] = o;
    }
  }
}

// ---------------- decoder: 16 WGs x 512 thr, 48 steps + per-step counter sync ----------------
__global__ __attribute__((amdgpu_flat_work_group_size(512, 512), amdgpu_waves_per_eu(2)))
void dec_kernel(P p) {
  __shared__ f16 sW0[24576];     // kt0 W (49152 B)
  __shared__ f16 sH[8192];
  __shared__ f16 sDin[1024];     // [16][64] f16, swizzled by (m&7)<<4
  __shared__ float sRed[512];
  __shared__ float sOutv[16];
  __shared__ float sO32[16];
  const int tid = threadIdx.x;
  const int l = tid & 63, w = tid >> 6;
  const int g = l >> 4, m16 = l & 15;
  const int sw16 = (m16 & 7) << 4;
  const int swzA = SWZ(m16);
  const int bg = blockIdx.x * 16;

  { // stage kt0 W
    const int4* src = (const int4*)(p.wdecf);
    int4* dst = (int4*)sW0;
#pragma unroll
    for (int i = 0; i < 6; ++i) dst[tid + i * 512] = src[tid + i * 512];
  }
  { // h <- h_enc (swizzled), buffer 0
    const int m = tid & 15, grp = tid >> 4;
    const f16x8 hv = *(const f16x8*)(p.henc + (size_t)(bg + m) * 256 + 8 * grp);
    *(f16x8*)((char*)sH + m * 512 + ((16 * grp) ^ SWZ(m))) = hv;
  }
  if (tid < 128) ((int4*)sDin)[tid] = int4{0, 0, 0, 0};
  const int nts[6] = {w, 8 + w, 16 + w, 24 + w, 32 + w, 40 + w};
  f16x8 Wr[8][6];
#pragma unroll
  for (int kt = 1; kt <= 8; ++kt)
#pragma unroll
    for (int i = 0; i < 6; ++i)
      Wr[kt - 1][i] = *(const f16x8*)(p.wdecf + ((size_t)(kt * 48 + nts[i]) * 64 + l) * 8);
  const int J1 = 16 * w + m16, J2 = 128 + J1;
  const float br1 = p.bD[J1], bz1 = p.bD[256 + J1], bi1 = p.bD[512 + J1], bh1 = p.bD[768 + J1];
  const float br2 = p.bD[J2], bz2 = p.bD[256 + J2], bi2 = p.bD[512 + J2], bh2 = p.bD[768 + J2];
  const float w32r1 = p.w32[J1], w32z1 = p.w32[256 + J1], w32n1 = p.w32[512 + J1];
  const float w32r2 = p.w32[J2], w32z2 = p.w32[256 + J2], w32n2 = p.w32[512 + J2];
  float hp1[4], hp2[4];
#pragma unroll
  for (int q = 0; q < 4; ++q) {
    hp1[q] = (float)p.henc[(size_t)(bg + 4 * g + q) * 256 + J1];
    hp2[q] = (float)p.henc[(size_t)(bg + 4 * g + q) * 256 + J2];
  }
  // eout -> sOutv, push stats for step 0
  if (tid < 16) sOutv[tid] = p.eout[bg + tid];
  __syncthreads();
  if (tid == 0) {
    float s1 = 0.f, s2 = 0.f;
#pragma unroll
    for (int k = 0; k < 16; ++k) { const float v = sOutv[k]; s1 += v; s2 += v * v; }
    atomicAdd(&p.ost[0], s1);
    atomicAdd(&p.ost[1], s2);
    __hip_atomic_fetch_add(&p.cnt[0], 1, __ATOMIC_RELEASE, __HIP_MEMORY_SCOPE_AGENT);
  }

  int ph = 0;
#pragma unroll 1
  for (int t = 0; t < 48; ++t) {
    // prefetch BN inputs for this step (no dependence on the counter)
    const int mp = tid & 15, cp = tid >> 4;
    const float xq = (float)p.decin[((size_t)t * 256 + bg + mp) * 32 + cp];
    const float mx = p.xst[(t * 32 + cp) * 2], vx = p.xst[(t * 32 + cp) * 2 + 1];
    const float gc = (t == 0) ? p.bn1g[cp] : p.bnTg[(t - 1) * 33 + cp];
    const float bc = (t == 0) ? p.bn1b[cp] : p.bnTb[(t - 1) * 33 + cp];
    float gK = 0.f, bK = 0.f;
    if (tid < 16) {
      gK = (t == 0) ? p.bn1g[32] : p.bnTg[(t - 1) * 33 + 32];
      bK = (t == 0) ? p.bn1b[32] : p.bnTb[(t - 1) * 33 + 32];
    }
    // (a) h-part MFMAs first (no dinp dependency)
    f32x4 aR0 = {0,0,0,0}, aR1 = {0,0,0,0}, aZ0 = {0,0,0,0}, aZ1 = {0,0,0,0};
    f32x4 aNh0 = {0,0,0,0}, aNh1 = {0,0,0,0};
#pragma unroll
    for (int kk = 1; kk <= 8; ++kk) {
      const f16x8 a = *(const f16x8*)((const char*)sH + ph * 8192 + m16 * 512 +
                                      ((64 * (kk - 1) + 16 * g) ^ swzA));
      aR0 = MFMA16(a, Wr[kk - 1][0], aR0);
      aR1 = MFMA16(a, Wr[kk - 1][1], aR1);
      aZ0 = MFMA16(a, Wr[kk - 1][2], aZ0);
      aZ1 = MFMA16(a, Wr[kk - 1][3], aZ1);
      aNh0 = MFMA16(a, Wr[kk - 1][4], aNh0);
      aNh1 = MFMA16(a, Wr[kk - 1][5], aNh1);
    }
    // (b) wait for batch stats of this step, then build sO32 + sDin
    if (tid == 0) {
      while (__hip_atomic_load(&p.cnt[t], __ATOMIC_ACQUIRE, __HIP_MEMORY_SCOPE_AGENT) < 16)
        __builtin_amdgcn_s_sleep(1);
    }
    __syncthreads();
    if (tid < 16) {
      const float S1 = __hip_atomic_load(&p.ost[2 * t], __ATOMIC_RELAXED, __HIP_MEMORY_SCOPE_AGENT);
      const float S2 = __hip_atomic_load(&p.ost[2 * t + 1], __ATOMIC_RELAXED, __HIP_MEMORY_SCOPE_AGENT);
      const float mu = S1 * (1.0f / 256.0f);
      const float var = S2 * (1.0f / 256.0f) - mu * mu;
      sO32[tid] = gK * (sOutv[tid] - mu) * rsqf_(var + 1e-5f) + bK;
    }
    *(f16*)((char*)sDin + mp * 128 + ((2 * cp) ^ ((mp & 7) << 4))) =
        (f16)(gc * (xq - mx) * rsqf_(vx + 1e-5f) + bc);
    __syncthreads();
    // (c) kt0 on dinp (W from LDS), then epilogue with rank-1 out-channel term
    f32x4 aNi0 = {0,0,0,0}, aNi1 = {0,0,0,0};
    {
      const f16x8 a = *(const f16x8*)((const char*)sDin + m16 * 128 + ((16 * g) ^ sw16));
      const char* wb = (const char*)sW0;
      { const f16x8 q = *(const f16x8*)(wb + (nts[0] * 64 + l) * 16); aR0 = MFMA16(a, q, aR0); }
      { const f16x8 q = *(const f16x8*)(wb + (nts[1] * 64 + l) * 16); aR1 = MFMA16(a, q, aR1); }
      { const f16x8 q = *(const f16x8*)(wb + (nts[2] * 64 + l) * 16); aZ0 = MFMA16(a, q, aZ0); }
      { const f16x8 q = *(const f16x8*)(wb + (nts[3] * 64 + l) * 16); aZ1 = MFMA16(a, q, aZ1); }
      { const f16x8 q = *(const f16x8*)(wb + (nts[4] * 64 + l) * 16); aNi0 = MFMA16(a, q, aNi0); }
      { const f16x8 q = *(const f16x8*)(wb + (nts[5] * 64 + l) * 16); aNi1 = MFMA16(a, q, aNi1); }
    }
    {
      char* hw = (char*)sH + (ph ^ 1) * 8192;
#pragma unroll
      for (int q = 0; q < 4; ++q) {
        const int m = 4 * g + q;
        const int sw = SWZ(m);
        const float o32m = sO32[m];
        const float r1 = sigf(aR0[q] + br1 + o32m * w32r1);
        const float z1 = sigf(aZ0[q] + bz1 + o32m * w32z1);
        const float n1 = tanhf_(aNi0[q] + bi1 + o32m * w32n1 + r1 * (aNh0[q] + bh1));
        const f16 h1 = (f16)(n1 + z1 * (hp1[q] - n1));
        hp1[q] = (float)h1;
        *(f16*)(hw + m * 512 + ((2 * J1) ^ sw)) = h1;
        const float r2 = sigf(aR1[q] + br2 + o32m * w32r2);
        const float z2 = sigf(aZ1[q] + bz2 + o32m * w32z2);
        const float n2 = tanhf_(aNi1[q] + bi2 + o32m * w32n2 + r2 * (aNh1[q] + bh2));
        const f16 h2 = (f16)(n2 + z2 * (hp2[q] - n2));
        hp2[q] = (float)h2;
        *(f16*)(hw + m * 512 + ((2 * J2) ^ sw)) = h2;
      }
    }
    __syncthreads();   // h_new complete
    // (d) out = h_new @ Wo + bo; push stats for t+1
    {
      const int m = tid & 15, grp = tid >> 4;
      const char* hb = (const char*)sH + (ph ^ 1) * 8192;
      const f16x8 hv = *(const f16x8*)(hb + m * 512 + ((16 * grp) ^ SWZ(m)));
      float part = 0.f;
#pragma unroll
      for (int jj = 0; jj < 8; ++jj) part += (float)hv[jj] * p.dWo[8 * grp + jj];
      sRed[m * 32 + grp] = part;
    }
    __syncthreads();
    if (tid < 16) {
      float o = p.dbo[0];
#pragma unroll 8
      for (int k = 0; k < 32; ++k) o += sRed[tid * 32 + k];
      p.out[(size_t)(bg + tid) * 48 + t] = o;
      sOutv[tid] = o;
    }
    __syncthreads();
    if (t < 47 && tid == 0) {
      float s1 = 0.f, s2 = 0.f;
#pragma unroll
      for (int k = 0; k < 16; ++k) { const float v = sOutv[k]; s1 += v; s2 += v * v; }
      atomicAdd(&p.ost[2 * (t + 1)], s1);
      atomicAdd(&p.ost[2 * (t + 1) + 1], s2);
      __hip_atomic_fetch_add(&p.cnt[t + 1], 1, __ATOMIC_RELEASE, __HIP_MEMORY_SCOPE_AGENT);
    }
    ph ^= 1;
  }
}

// ---------------- launcher ----------------
extern "C" void kernel_launch(void* const* d_in, const int* in_sizes, int n_in,
                              void* d_out, int out_size, void* d_ws, size_t ws_size,
                              hipStream_t stream) {
  char* ws = (char*)d_ws;
  P p;
  p.Xe   = (const float*)d_in[0];
  p.Xd   = (const float*)d_in[1];
  p.Xge  = (const float*)d_in[2];
  p.Xgd  = (const float*)d_in[3];
  p.Wge  = (const float*)d_in[4];
  p.bge  = (const float*)d_in[5];
  p.Wgd  = (const float*)d_in[6];
  p.bgd  = (const float*)d_in[7];
  p.eWih = (const float*)d_in[8];
  p.eWhh = (const float*)d_in[9];
  p.ebih = (const float*)d_in[10];
  p.ebhh = (const float*)d_in[11];
  p.eWo  = (const float*)d_in[12];
  p.ebo  = (const float*)d_in[13];
  p.dWih = (const float*)d_in[14];
  p.dWhh = (const float*)d_in[15];
  p.dbih = (const float*)d_in[16];
  p.dbhh = (const float*)d_in[17];
  p.dWo  = (const float*)d_in[18];
  p.dbo  = (const float*)d_in[19];
  p.bn1g = (const float*)d_in[20];
  p.bn1b = (const float*)d_in[21];
  p.bnTg = (const float*)d_in[22];
  p.bnTb = (const float*)d_in[23];
  p.encin = (f16*)(ws + OFF_ENCIN);
  p.decin = (f16*)(ws + OFF_DECIN);
  p.wencf = (f16*)(ws + OFF_WENC);
  p.wdecf = (f16*)(ws + OFF_WDEC);
  p.w32   = (float*)(ws + OFF_W32);
  p.bE    = (float*)(ws + OFF_BE);
  p.bD    = (float*)(ws + OFF_BD);
  p.henc  = (f16*)(ws + OFF_HENC);
  p.eout  = (float*)(ws + OFF_EOUT);
  p.xst   = (float*)(ws + OFF_XST);
  p.ost   = (float*)(ws + OFF_OST);
  p.cnt   = (int*)(ws + OFF_CNT);
  p.out   = (float*)d_out;

  prep1<<<dim3(1291), dim3(256), 0, stream>>>(p);
  prep2<<<dim3(6), dim3(256), 0, stream>>>(p);
  enc_kernel<<<dim3(16), dim3(512), 0, stream>>>(p);
  dec_kernel<<<dim3(16), dim3(512), 0, stream>>>(p);
}